// Round 18
// baseline (57.375 us; speedup 1.0000x reference)
//
#include <hip/hip_runtime.h>

#define HW 2112L            // 64*33
typedef float f32x4 __attribute__((ext_vector_type(4)));
typedef short s16x8 __attribute__((ext_vector_type(8)));

// ws: W B-fragment planes. 512 modes * 2 ntiles * 64 lanes * 8 bf16 * 2B = 1 MB/plane.
#define WT_PLANE 1048576L
#define OFF_WHR 0L
#define OFF_WLR (WT_PLANE)
#define OFF_WHI (2*WT_PLANE)
#define OFF_WLI (3*WT_PLANE)

__device__ __forceinline__ ushort f2bf(float f) {
    unsigned u = __float_as_uint(f);
    u += 0x7FFF + ((u >> 16) & 1);          // RNE to bf16
    return (ushort)(u >> 16);
}
__device__ __forceinline__ void split_bf(float v, ushort& hi, ushort& lo) {
    hi = f2bf(v);
    float hf = __uint_as_float(((unsigned)hi) << 16);
    lo = f2bf(v - hf);
}

// =============== K1: wprep role (64 blocks) + middle-band fill (1984 blocks) ===============
// (verbatim from R10, the 34.0 champion)
__global__ __launch_bounds__(256) void k1_prep_fill(
    const float* __restrict__ w1_re, const float* __restrict__ w1_im,
    const float* __restrict__ w2_re, const float* __restrict__ w2_im,
    float* __restrict__ out, char* __restrict__ ws)
{
    const int tid = threadIdx.x, bid = blockIdx.x;

    if (bid >= 64) {
        const int fid = bid - 64;                 // [0,1984)
        int gtid = fid * 256 + tid, n = 1984 * 256;
        float4* out4 = (float4*)out;
        const float4 z = make_float4(0.f, 0.f, 0.f, 0.f);
        for (int idx = gtid; idx < 4096 * 528; idx += n) {
            int plane = idx / 528;
            int k = idx - plane * 528;
            out4[(long)plane * 1056 + 264 + k] = z;
        }
        return;
    }

    const int r = bid >> 5, i = (bid >> 1) & 15, nt = bid & 1;
    const float* wre = r ? w2_re : w1_re;
    const float* wim = r ? w2_im : w1_im;
    const int col = tid >> 4, j = tid & 15, o = nt * 16 + col;
    const int modeLin = (r * 16 + i) * 16 + j;
    s16x8* phr = (s16x8*)(ws + OFF_WHR);
    s16x8* plr = (s16x8*)(ws + OFF_WLR);
    s16x8* phi = (s16x8*)(ws + OFF_WHI);
    s16x8* pli = (s16x8*)(ws + OFF_WLI);
    #pragma unroll
    for (int kg = 0; kg < 4; ++kg) {
        s16x8 hr, lr, hi2, li2;
        #pragma unroll
        for (int e = 0; e < 8; ++e) {
            int c = kg * 8 + e;
            long src = ((long)(c * 32 + o) * 16 + i) * 16 + j;
            ushort a, b;
            split_bf(wre[src], a, b); hr[e] = (short)a; lr[e] = (short)b;
            split_bf(wim[src], a, b); hi2[e] = (short)a; li2[e] = (short)b;
        }
        long off = (long)(modeLin * 2 + nt) * 64 + kg * 16 + col;
        phr[off] = hr; plr[off] = lr; phi[off] = hi2; pli[off] = li2;
    }
}

// =============== K2: 1024 blocks x 2 tiles (BLPB=2), x-read pipelined across tiles ===============
__global__ __launch_bounds__(256, 4) void k2_compute(
    const float* __restrict__ x_re, const float* __restrict__ x_im,
    float* __restrict__ out, const char* __restrict__ ws)
{
    const int tid = threadIdx.x, bid = blockIdx.x;
    const int r = bid >> 9, i = (bid >> 5) & 15, bp = bid & 31;
    const int h = r ? 48 + i : i;
    const int modeBase = (r * 16 + i) * 16;

    __shared__ __align__(16) ushort xf[2][2][16][2][32];  // [tile][re/im][j][bl][c] 8 KB
    __shared__ __align__(16) float2 stg[64][17];          // [bl*32+o][j] 8.7 KB

    const int wave = tid >> 6, lane = tid & 63;
    const int m = lane & 1, ks = lane >> 4, colo = lane & 15;

    const s16x8* Bwhr = (const s16x8*)(ws + OFF_WHR);
    const s16x8* Bwlr = (const s16x8*)(ws + OFF_WLR);
    const s16x8* Bwhi = (const s16x8*)(ws + OFF_WHI);
    const s16x8* Bwli = (const s16x8*)(ws + OFF_WLI);

    // thread's stage coords (fixed for both tiles)
    const int sj4 = tid & 3, sc = (tid >> 2) & 31, sbl = tid >> 7;

    s16x8 cBhr[2], cBlr[2], cBhi[2], cBli[2];

    // ---- prefetch B jj=0 + T0 x loads ----
    {
        long b0 = ((long)(modeBase + wave * 4) * 2 + 0) * 64 + lane;
        long b1 = ((long)(modeBase + wave * 4) * 2 + 1) * 64 + lane;
        cBhr[0] = Bwhr[b0]; cBlr[0] = Bwlr[b0]; cBhi[0] = Bwhi[b0]; cBli[0] = Bwli[b0];
        cBhr[1] = Bwhr[b1]; cBlr[1] = Bwlr[b1]; cBhi[1] = Bwhi[b1]; cBli[1] = Bwli[b1];
    }

    f32x4 vr1, vi1;                       // T1 x regs, held through T0 compute

    #pragma unroll 1
    for (int T = 0; T < 2; ++T) {
        const int bl0 = bp * 4 + T * 2;

        if (T == 0) {
            // ---- stage T0 (blocking: load+convert+LDS) ----
            long base = ((long)((bl0 + sbl) * 32 + sc)) * HW + h * 33 + sj4 * 4;
            f32x4 vr = *(const f32x4*)&x_re[base];
            f32x4 vi = *(const f32x4*)&x_im[base];
            #pragma unroll
            for (int q = 0; q < 4; ++q) {
                xf[0][0][sj4 * 4 + q][sbl][sc] = f2bf(vr[q]);
                xf[0][1][sj4 * 4 + q][sbl][sc] = f2bf(vi[q]);
            }
            __syncthreads();
            // ---- issue T1 x loads NOW (land during T0 compute) ----
            long base1 = ((long)((bl0 + 2 + sbl) * 32 + sc)) * HW + h * 33 + sj4 * 4;
            vr1 = *(const f32x4*)&x_re[base1];
            vi1 = *(const f32x4*)&x_im[base1];
            __builtin_amdgcn_sched_barrier(0);   // keep the issues above the MFMA loop
        }

        // ---- compute tile T: 4 jj per wave, B pipelined 1 ahead ----
        #pragma unroll
        for (int jj = 0; jj < 4; ++jj) {
            const int j = wave * 4 + jj;

            s16x8 nBhr[2], nBlr[2], nBhi[2], nBli[2];
            if (jj < 3) {
                long b0 = ((long)(modeBase + j + 1) * 2 + 0) * 64 + lane;
                long b1 = ((long)(modeBase + j + 1) * 2 + 1) * 64 + lane;
                nBhr[0] = Bwhr[b0]; nBlr[0] = Bwlr[b0]; nBhi[0] = Bwhi[b0]; nBli[0] = Bwli[b0];
                nBhr[1] = Bwhr[b1]; nBlr[1] = Bwlr[b1]; nBhi[1] = Bwhi[b1]; nBli[1] = Bwli[b1];
            }

            s16x8 Ahr = *(const s16x8*)&xf[T][0][j][m][ks * 8];
            s16x8 Ahi = *(const s16x8*)&xf[T][1][j][m][ks * 8];

            #pragma unroll
            for (int nt = 0; nt < 2; ++nt) {
                f32x4 accP = (f32x4)0.0f, accN = (f32x4)0.0f, accI = (f32x4)0.0f;
                accP = __builtin_amdgcn_mfma_f32_16x16x32_bf16(Ahr, cBhr[nt], accP, 0, 0, 0);
                accP = __builtin_amdgcn_mfma_f32_16x16x32_bf16(Ahr, cBlr[nt], accP, 0, 0, 0);
                accN = __builtin_amdgcn_mfma_f32_16x16x32_bf16(Ahi, cBhi[nt], accN, 0, 0, 0);
                accN = __builtin_amdgcn_mfma_f32_16x16x32_bf16(Ahi, cBli[nt], accN, 0, 0, 0);
                accI = __builtin_amdgcn_mfma_f32_16x16x32_bf16(Ahr, cBhi[nt], accI, 0, 0, 0);
                accI = __builtin_amdgcn_mfma_f32_16x16x32_bf16(Ahr, cBli[nt], accI, 0, 0, 0);
                accI = __builtin_amdgcn_mfma_f32_16x16x32_bf16(Ahi, cBhr[nt], accI, 0, 0, 0);
                accI = __builtin_amdgcn_mfma_f32_16x16x32_bf16(Ahi, cBlr[nt], accI, 0, 0, 0);

                if (ks == 0) {                    // D rows repeat every 2 bl: rows 0,1 valid
                    #pragma unroll
                    for (int q = 0; q < 2; ++q)
                        stg[q * 32 + nt * 16 + colo][j] =
                            make_float2(accP[q] - accN[q], accI[q]);
                }
            }

            if (jj < 3) {
                #pragma unroll
                for (int nt = 0; nt < 2; ++nt) {
                    cBhr[nt] = nBhr[nt]; cBlr[nt] = nBlr[nt];
                    cBhi[nt] = nBhi[nt]; cBli[nt] = nBli[nt];
                }
            }
        }
        __syncthreads();                          // stg(T) ready

        if (T == 0) {
            // ---- store T1 stage (loads landed during compute) ----
            #pragma unroll
            for (int q = 0; q < 4; ++q) {
                xf[1][0][sj4 * 4 + q][sbl][sc] = f2bf(vr1[q]);
                xf[1][1][sj4 * 4 + q][sbl][sc] = f2bf(vi1[q]);
            }
            // ---- reload B jj=0 for T1 (L2-hot) ----
            long b0 = ((long)(modeBase + wave * 4) * 2 + 0) * 64 + lane;
            long b1 = ((long)(modeBase + wave * 4) * 2 + 1) * 64 + lane;
            cBhr[0] = Bwhr[b0]; cBlr[0] = Bwlr[b0]; cBhi[0] = Bwhi[b0]; cBli[0] = Bwli[b0];
            cBhr[1] = Bwhr[b1]; cBlr[1] = Bwlr[b1]; cBhi[1] = Bwhi[b1]; cBli[1] = Bwli[b1];
        }

        // ---- writeout tile T: 64 rows x 33 float2, tails fused ----
        float2* out2 = (float2*)out;
        #pragma unroll 2
        for (int t = 0; t < 9; ++t) {
            int idx = t * 256 + tid;              // [0,2304); valid < 2112
            if (idx < 64 * 33) {
                int row = idx / 33;               // bl*32 + o
                int k = idx - row * 33;
                int bl = row >> 5, o = row & 31;
                float2 v = (k < 16) ? stg[row][k] : make_float2(0.f, 0.f);
                long dst = ((long)((bl0 + bl) * 32 + o) * 64 + h) * 33 + k;
                out2[dst] = v;
            }
        }
        if (T == 0) __syncthreads();              // stg free + xf[1] ready
    }
}

extern "C" void kernel_launch(void* const* d_in, const int* in_sizes, int n_in,
                              void* d_out, int out_size, void* d_ws, size_t ws_size,
                              hipStream_t stream) {
    const float* x_re  = (const float*)d_in[0];
    const float* x_im  = (const float*)d_in[1];
    const float* w1_re = (const float*)d_in[2];
    const float* w1_im = (const float*)d_in[3];
    const float* w2_re = (const float*)d_in[4];
    const float* w2_im = (const float*)d_in[5];
    float* out = (float*)d_out;
    char* ws = (char*)d_ws;

    k1_prep_fill<<<dim3(2048), dim3(256), 0, stream>>>(
        w1_re, w1_im, w2_re, w2_im, out, ws);
    k2_compute<<<dim3(1024), dim3(256), 0, stream>>>(x_re, x_im, out, ws);
}